// Round 4
// baseline (167.846 us; speedup 1.0000x reference)
//
#include <hip/hip_runtime.h>

#define GAT_H 12
#define GAT_N 4096
#define GAT_F 64
#define TJ    64            // j per tile
#define NT    (GAT_N / TJ)  // 64 tiles
#define RPB   4             // rows per block
#define HPW   3             // heads per wave
#define LOG2E 1.4426950408889634f
#define TAB_OFF 1024        // float offset of table in d_ws

__device__ __forceinline__ float rfl(float v) {
    return __uint_as_float(__builtin_amdgcn_readfirstlane(__float_as_uint(v)));
}

// Prep: blocks 0..11 compute s_h = <W_h, a_src_h>, d_h = <W_h, a_dst_h>.
// Block 12 computes mean(x) (fallback for neighborless rows -> uniform attn).
__global__ __launch_bounds__(64) void gat_prep(const float* __restrict__ W,
                                               const float* __restrict__ a,
                                               const float* __restrict__ x,
                                               float* __restrict__ sd) {
    const int b = blockIdx.x;
    const int f = threadIdx.x;
    if (b < GAT_H) {
        const float wf = W[b * GAT_F + f];
        float ps = wf * a[b * 2 * GAT_F + f];
        float pd = wf * a[b * 2 * GAT_F + GAT_F + f];
        #pragma unroll
        for (int off = 32; off > 0; off >>= 1) {
            ps += __shfl_xor(ps, off, 64);
            pd += __shfl_xor(pd, off, 64);
        }
        if (f == 0) { sd[b] = ps; sd[GAT_H + b] = pd; }
    } else {
        float s = 0.0f;
        #pragma unroll
        for (int j = 0; j < GAT_N / 64; ++j) s += x[j * 64 + f];
        #pragma unroll
        for (int off = 32; off > 0; off >>= 1) s += __shfl_xor(s, off, 64);
        if (f == 0) sd[2 * GAT_H] = s * (1.0f / GAT_N);
    }
}

// Table per (j,h): {B,D} = {exp2(L*d_h*x_j), exp2(0.2L*d_h*x_j)}, swapped
// when d_h<0 so the consumer's compare direction is fixed (sel = x_j > U).
__global__ __launch_bounds__(256) void gat_tab(const float* __restrict__ x,
                                               const float* __restrict__ sd,
                                               float2* __restrict__ tab) {
    const int t  = blockIdx.x * 256 + threadIdx.x;   // 0..49151, layout [j][h]
    const int h  = t % GAT_H;
    const int jg = t / GAT_H;
    const float d = sd[GAT_H + h];
    const float q = LOG2E * d * x[jg];
    const float B = __builtin_amdgcn_exp2f(q);
    const float D = __builtin_amdgcn_exp2f(0.2f * q);
    tab[t] = (d > 0.0f) ? make_float2(B, D) : make_float2(D, B);
}

// Main: 1024 blocks x 256 thr. Block = 4 rows x all j; the 4 waves split the
// 12 heads (3 each) so accs = 4r*3h*2 = 24 VGPRs and NO cross-wave combine.
// Per-(row,head) constants U,RA are wave-uniform -> SGPRs (readfirstlane);
// the per-row branch factor cancels in num/den so A,C are never needed.
// Body per (j,r,h): v_mul(sgpr) + v_cmp(sgpr) + cndmask + 2 fma. No trans.
__global__ __launch_bounds__(256) void gat_main(const float* __restrict__ x,
                                                const int* __restrict__ adj,
                                                const float* __restrict__ W,
                                                const float* __restrict__ sd,
                                                const float2* __restrict__ tab,
                                                float* __restrict__ out) {
    __shared__ float2 tb[2][TJ * 13];   // 13-pad: lane stride 26 dw -> <=2-way
    __shared__ int    ab[2][RPB * TJ];

    const int tid  = threadIdx.x;
    const int lane = tid & 63;
    const int wq   = tid >> 6;
    const int row0 = blockIdx.x * RPB;

    // Wave-uniform per (r,k): threshold U and ratio RA = exp2(-+0.8*L*zi).
    float sU[RPB][HPW], sRA[RPB][HPW];
    #pragma unroll
    for (int r = 0; r < RPB; ++r) {
        const float xi = x[row0 + r];
        #pragma unroll
        for (int k = 0; k < HPW; ++k) {
            const int h    = wq * HPW + k;
            const float dh = sd[GAT_H + h];
            const float zi = xi * sd[h];
            sU[r][k]  = rfl(-zi * __builtin_amdgcn_rcpf(dh));
            sRA[r][k] = rfl(__builtin_amdgcn_exp2f(((dh > 0.f) ? -0.8f : 0.8f) * LOG2E * zi));
        }
    }

    float den[RPB][HPW], num[RPB][HPW];
    #pragma unroll
    for (int r = 0; r < RPB; ++r)
        #pragma unroll
        for (int k = 0; k < HPW; ++k) { den[r][k] = 0.0f; num[r][k] = 0.0f; }

    // Staging maps (constant across tiles). Thread stages 3 table pairs + 1 adj.
    int slot[3];
    #pragma unroll
    for (int kk = 0; kk < 3; ++kk) {
        const int p = kk * 256 + tid;
        slot[kk] = (p / GAT_H) * 13 + (p % GAT_H);
    }
    const float2* __restrict__ tgp = tab + tid;                       // +kk*256 +T*768
    const int*    __restrict__ agp = adj + (size_t)(row0 + wq) * GAT_N + lane;  // +T*64

    // Prologue: stage tile 0 into buffer 0.
    float2 tv[3];
    int av;
    #pragma unroll
    for (int kk = 0; kk < 3; ++kk) tv[kk] = tgp[kk * 256];
    av = agp[0];
    #pragma unroll
    for (int kk = 0; kk < 3; ++kk) tb[0][slot[kk]] = tv[kk];
    ab[0][tid] = av;
    __syncthreads();

    for (int T = 0; T < NT; ++T) {
        const int b = T & 1;
        if (T < NT - 1) {   // prefetch next tile into registers (hides L2 lat)
            #pragma unroll
            for (int kk = 0; kk < 3; ++kk)
                tv[kk] = tgp[(T + 1) * (TJ * GAT_H) + kk * 256];
            av = agp[(T + 1) * TJ];
        }

        const float xj = x[T * TJ + lane];
        float2 P[HPW];
        #pragma unroll
        for (int k = 0; k < HPW; ++k) P[k] = tb[b][lane * 13 + wq * HPW + k];
        int ar[RPB];
        #pragma unroll
        for (int r = 0; r < RPB; ++r) ar[r] = ab[b][r * TJ + lane];

        #pragma unroll
        for (int r = 0; r < RPB; ++r) {
            const float m01 = (float)ar[r];     // adj in {0,1}: one v_cvt
            const float xm  = xj * m01;
            #pragma unroll
            for (int k = 0; k < HPW; ++k) {
                const bool  sel = xj > sU[r][k];
                const float E   = sel ? P[k].x : P[k].y * sRA[r][k];
                den[r][k] = fmaf(E, m01, den[r][k]);
                num[r][k] = fmaf(E, xm,  num[r][k]);
            }
        }

        if (T < NT - 1) {   // write prefetched tile into the other buffer
            #pragma unroll
            for (int kk = 0; kk < 3; ++kk) tb[1 - b][slot[kk]] = tv[kk];
            ab[1 - b][tid] = av;
        }
        __syncthreads();
    }

    // Epilogue: each wave owns full j-sums for its (r, h) cells.
    const float xmean = sd[2 * GAT_H];
    #pragma unroll
    for (int r = 0; r < RPB; ++r) {
        const size_t base = (size_t)(row0 + r) * (GAT_H * GAT_F);
        #pragma unroll
        for (int k = 0; k < HPW; ++k) {
            float dn = den[r][k], nm = num[r][k];
            #pragma unroll
            for (int off = 32; off > 0; off >>= 1) {
                dn += __shfl_xor(dn, off, 64);
                nm += __shfl_xor(nm, off, 64);
            }
            const int h = wq * HPW + k;
            const float c = dn > 0.0f ? nm * __builtin_amdgcn_rcpf(dn) : xmean;
            out[base + h * GAT_F + lane] = c * W[h * GAT_F + lane];
        }
    }
}

extern "C" void kernel_launch(void* const* d_in, const int* in_sizes, int n_in,
                              void* d_out, int out_size, void* d_ws, size_t ws_size,
                              hipStream_t stream) {
    const float* x   = (const float*)d_in[0];
    const int*   adj = (const int*)d_in[1];
    const float* W   = (const float*)d_in[2];
    const float* a   = (const float*)d_in[3];
    float* out  = (float*)d_out;
    float* sd   = (float*)d_ws;                        // 25 floats
    float2* tab = (float2*)((float*)d_ws + TAB_OFF);   // 4096*12 float2 = 384 KB

    gat_prep<<<13, 64, 0, stream>>>(W, a, x, sd);
    gat_tab<<<(GAT_N * GAT_H) / 256, 256, 0, stream>>>(x, sd, tab);
    gat_main<<<GAT_N / RPB, 256, 0, stream>>>(x, adj, W, sd, tab, out);
}

// Round 5
// 162.532 us; speedup vs baseline: 1.0327x; 1.0327x over previous
//
#include <hip/hip_runtime.h>

#define GAT_H 12
#define GAT_N 4096
#define GAT_F 64
#define TJ    64
#define NT    (GAT_N / TJ)   // 64 tiles
#define RPB   2              // rows per block
#define HPW   3              // heads per wave
#define PFA   4              // adj prefetch depth (tiles)
#define LOG2E 1.4426950408889634f
#define TAB_OFF 1024         // float offset of table in d_ws

__device__ __forceinline__ float rfl(float v) {
    return __uint_as_float(__builtin_amdgcn_readfirstlane(__float_as_uint(v)));
}

// Prep: blocks 0..11 compute s_h = <W_h, a_src_h>, d_h = <W_h, a_dst_h>.
// Block 12 computes mean(x) (fallback for neighborless rows -> uniform attn).
__global__ __launch_bounds__(64) void gat_prep(const float* __restrict__ W,
                                               const float* __restrict__ a,
                                               const float* __restrict__ x,
                                               float* __restrict__ sd) {
    const int b = blockIdx.x;
    const int f = threadIdx.x;
    if (b < GAT_H) {
        const float wf = W[b * GAT_F + f];
        float ps = wf * a[b * 2 * GAT_F + f];
        float pd = wf * a[b * 2 * GAT_F + GAT_F + f];
        #pragma unroll
        for (int off = 32; off > 0; off >>= 1) {
            ps += __shfl_xor(ps, off, 64);
            pd += __shfl_xor(pd, off, 64);
        }
        if (f == 0) { sd[b] = ps; sd[GAT_H + b] = pd; }
    } else {
        float s = 0.0f;
        #pragma unroll
        for (int j = 0; j < GAT_N / 64; ++j) s += x[j * 64 + f];
        #pragma unroll
        for (int off = 32; off > 0; off >>= 1) s += __shfl_xor(s, off, 64);
        if (f == 0) sd[2 * GAT_H] = s * (1.0f / GAT_N);
    }
}

// Table, tile-blocked layout [T][h][jloc] (T=j/64): per (j,h) pair
// {B,D} = {exp2(L*d_h*x_j), exp2(0.2L*d_h*x_j)}, swapped when d_h<0 so the
// consumer's compare (sel = x_j > U) is direction-fixed.
__global__ __launch_bounds__(256) void gat_tab(const float* __restrict__ x,
                                               const float* __restrict__ sd,
                                               float2* __restrict__ tab) {
    const int t  = blockIdx.x * 256 + threadIdx.x;   // 0..49151
    const int T  = t / (GAT_H * TJ);
    const int h  = (t / TJ) % GAT_H;
    const int jl = t % TJ;
    const float d = sd[GAT_H + h];
    const float q = LOG2E * d * x[T * TJ + jl];
    const float B = __builtin_amdgcn_exp2f(q);
    const float D = __builtin_amdgcn_exp2f(0.2f * q);
    tab[t] = (d > 0.0f) ? make_float2(B, D) : make_float2(D, B);
}

// Main: 2048 blocks x 256 thr (4 waves). Block = 2 rows; waves split heads
// (3 each) so each wave owns complete j-sums for its (r,h) cells.
// adj: private per-wave 4-deep register pipeline (no LDS, no barrier dep).
// table: [h][j] LDS tiles, double-buffered, 2-deep reg prefetch, 1 barrier/tile.
// Body per (j,r,h): v_mul + v_cmp(sgpr) + v_cndmask + 2 v_fma. No trans.
__global__ __launch_bounds__(256) void gat_main(const float* __restrict__ x,
                                                const int* __restrict__ adj,
                                                const float* __restrict__ W,
                                                const float* __restrict__ sd,
                                                const float2* __restrict__ tab,
                                                float* __restrict__ out) {
    __shared__ float  xs[GAT_N];            // 16 KB
    __shared__ float2 tb[2][GAT_H * TJ];    // 2 x 6 KB, [h][jloc]

    const int tid  = threadIdx.x;
    const int lane = tid & 63;
    const int wq   = tid >> 6;
    const int row0 = blockIdx.x * RPB;

    #pragma unroll
    for (int it = 0; it < GAT_N / (256 * 4); ++it)
        ((float4*)xs)[it * 256 + tid] = ((const float4*)x)[it * 256 + tid];

    // Wave-uniform per (r,k): threshold U and ratio RA = exp2(-+0.8*L*zi).
    float sU[RPB][HPW], sRA[RPB][HPW];
    #pragma unroll
    for (int r = 0; r < RPB; ++r) {
        const float xi = x[row0 + r];
        #pragma unroll
        for (int k = 0; k < HPW; ++k) {
            const int h    = wq * HPW + k;
            const float dh = sd[GAT_H + h];
            const float zi = xi * sd[h];
            sU[r][k]  = rfl(-zi * __builtin_amdgcn_rcpf(dh));
            sRA[r][k] = rfl(__builtin_amdgcn_exp2f(((dh > 0.f) ? -0.8f : 0.8f) * LOG2E * zi));
        }
    }

    float den[RPB][HPW], num[RPB][HPW];
    #pragma unroll
    for (int r = 0; r < RPB; ++r)
        #pragma unroll
        for (int k = 0; k < HPW; ++k) { den[r][k] = 0.0f; num[r][k] = 0.0f; }

    const float2* __restrict__ tg  = tab + tid;  // +k*256 (+T*768)
    const int*    __restrict__ ag0 = adj + (size_t)row0 * GAT_N + lane;
    const int*    __restrict__ ag1 = adj + (size_t)(row0 + 1) * GAT_N + lane;

    // adj prologue: 4-deep register pipeline.
    int av0[PFA], av1[PFA];
    #pragma unroll
    for (int u = 0; u < PFA; ++u) { av0[u] = ag0[u * TJ]; av1[u] = ag1[u * TJ]; }

    // Table prologue: tile 0 -> LDS buf 0; tile 1 -> regs.
    float2 tv[3];
    #pragma unroll
    for (int k = 0; k < 3; ++k) tv[k] = tg[k * 256];
    #pragma unroll
    for (int k = 0; k < 3; ++k) tb[0][k * 256 + tid] = tv[k];
    #pragma unroll
    for (int k = 0; k < 3; ++k) tv[k] = tg[768 + k * 256];
    __syncthreads();

    for (int Tb = 0; Tb < NT; Tb += 4) {
        #pragma unroll
        for (int u = 0; u < 4; ++u) {
            const int T = Tb + u;
            const int b = T & 1;

            // Window T: write tile T+1 (regs, loaded window T-1) to other buf;
            // refill regs with tile T+2. One barrier at window end.
            if (T < NT - 1) {
                #pragma unroll
                for (int k = 0; k < 3; ++k) tb[1 - b][k * 256 + tid] = tv[k];
            }
            if (T < NT - 2) {
                #pragma unroll
                for (int k = 0; k < 3; ++k) tv[k] = tg[(T + 2) * 768 + k * 256];
            }

            const float xj = xs[T * TJ + lane];
            float2 P[HPW];
            #pragma unroll
            for (int k = 0; k < HPW; ++k) P[k] = tb[b][(wq * HPW + k) * TJ + lane];

            const float m0 = (float)av0[u];   // adj in {0,1}: one v_cvt
            const float m1 = (float)av1[u];
            {   // refill adj pipeline for tile T+PFA (clamped, unused if OOB)
                const int nT = (T + PFA < NT) ? (T + PFA) : (NT - 1);
                av0[u] = ag0[nT * TJ];
                av1[u] = ag1[nT * TJ];
            }
            const float xm0 = xj * m0;
            const float xm1 = xj * m1;
            #pragma unroll
            for (int k = 0; k < HPW; ++k) {
                const bool  s0 = xj > sU[0][k];
                const float E0 = s0 ? P[k].x : P[k].y * sRA[0][k];
                den[0][k] = fmaf(E0, m0, den[0][k]);
                num[0][k] = fmaf(E0, xm0, num[0][k]);
                const bool  s1 = xj > sU[1][k];
                const float E1 = s1 ? P[k].x : P[k].y * sRA[1][k];
                den[1][k] = fmaf(E1, m1, den[1][k]);
                num[1][k] = fmaf(E1, xm1, num[1][k]);
            }
            __syncthreads();
        }
    }

    // Epilogue: each wave owns full j-sums for its (r,h) cells.
    const float xmean = sd[2 * GAT_H];
    #pragma unroll
    for (int r = 0; r < RPB; ++r) {
        const size_t base = (size_t)(row0 + r) * (GAT_H * GAT_F);
        #pragma unroll
        for (int k = 0; k < HPW; ++k) {
            float dn = den[r][k], nm = num[r][k];
            #pragma unroll
            for (int off = 32; off > 0; off >>= 1) {
                dn += __shfl_xor(dn, off, 64);
                nm += __shfl_xor(nm, off, 64);
            }
            const int h = wq * HPW + k;
            const float c = dn > 0.0f ? nm * __builtin_amdgcn_rcpf(dn) : xmean;
            out[base + h * GAT_F + lane] = c * W[h * GAT_F + lane];
        }
    }
}

extern "C" void kernel_launch(void* const* d_in, const int* in_sizes, int n_in,
                              void* d_out, int out_size, void* d_ws, size_t ws_size,
                              hipStream_t stream) {
    const float* x   = (const float*)d_in[0];
    const int*   adj = (const int*)d_in[1];
    const float* W   = (const float*)d_in[2];
    const float* a   = (const float*)d_in[3];
    float* out  = (float*)d_out;
    float* sd   = (float*)d_ws;                        // 25 floats
    float2* tab = (float2*)((float*)d_ws + TAB_OFF);   // 4096*12 float2 = 384 KB

    gat_prep<<<13, 64, 0, stream>>>(W, a, x, sd);
    gat_tab<<<(GAT_N * GAT_H) / 256, 256, 0, stream>>>(x, sd, tab);
    gat_main<<<GAT_N / RPB, 256, 0, stream>>>(x, adj, W, sd, tab, out);
}